// Round 10
// baseline (230.811 us; speedup 1.0000x reference)
//
#include <hip/hip_runtime.h>
#include <math.h>

// Problem constants (reference: T,B,E,H = 1024,4,1024,16; DH=64; 32 buckets, max_dist 128)
#define T_ 1024
#define B_ 4
#define E_ 1024
#define H_ 16
#define DH_ 64

#define LOG2E 1.44269504088896f

typedef __attribute__((ext_vector_type(8))) __bf16 bf16x8;
typedef __attribute__((ext_vector_type(4))) __bf16 bf16x4;
typedef __attribute__((ext_vector_type(4))) float f32x4;

// fp32 -> bf16 round-to-nearest-even
__device__ __forceinline__ __bf16 f2bf(float x){
  union { unsigned short u; __bf16 b; } cv;
  unsigned u32 = __float_as_uint(x);
  cv.u = (unsigned short)((u32 + 0x7fffu + ((u32 >> 16) & 1u)) >> 16);
  return cv.b;
}
// fp32 -> bf16 round-half-up (cheaper; used only for P >= 0)
__device__ __forceinline__ __bf16 f2bf_fast(float x){
  union { unsigned short u; __bf16 b; } cv;
  cv.u = (unsigned short)((__float_as_uint(x) + 0x8000u) >> 16);
  return cv.b;
}

// async global->LDS, 16B per lane; LDS dest is wave-uniform base + lane*16 (m97/m104)
__device__ __forceinline__ void glds16(const void* g, void* l){
  __builtin_amdgcn_global_load_lds(
      (__attribute__((address_space(1))) void*)(void*)g,
      (__attribute__((address_space(3))) void*)l,
      16, 0, 0);
}

// ---------------- prep: weight cvt (blocks 0..4095) + gates/qbf (4096..4351) + tab (4352..4479) ----------------
__global__ __launch_bounds__(256) void prep_kernel(
    const float* __restrict__ q_w, const float* __restrict__ k_w,
    const float* __restrict__ v_w, const float* __restrict__ out_w,
    __bf16* __restrict__ wq, __bf16* __restrict__ wk,
    __bf16* __restrict__ wv, __bf16* __restrict__ wo,
    const float* __restrict__ query, const float* __restrict__ gw,
    const float* __restrict__ gb, const float* __restrict__ ga,
    float* __restrict__ gates, __bf16* __restrict__ qbf,
    const float* __restrict__ rel_bias, float* __restrict__ tab)
{
  const int bid = blockIdx.x;
  const int tid = threadIdx.x;
  if (bid < 4096){
    const float* a; __bf16* o;
    switch (bid >> 10){
      case 0: a = q_w;  o = wq; break;
      case 1: a = k_w;  o = wk; break;
      case 2: a = v_w;  o = wv; break;
      default: a = out_w; o = wo; break;
    }
    int i = ((bid & 1023) * 256 + tid) * 4;
    float4 v = *(const float4*)(a + i);
    bf16x4 r;
    r[0] = f2bf(v.x); r[1] = f2bf(v.y); r[2] = f2bf(v.z); r[3] = f2bf(v.w);
    *(bf16x4*)(o + i) = r;
  } else if (bid < 4352){
    int t = (bid - 4096) * 4 + (tid >> 6);
    int bh = tid & 63;
    int h = bh & 15;
    const float* q = query + (size_t)t * E_ * B_ + bh * 64;
    __bf16* qo = qbf + (size_t)t * E_ * B_ + bh * 64;
    float g[8];
    #pragma unroll
    for (int e = 0; e < 8; e++) g[e] = gb[e];
    #pragma unroll
    for (int c = 0; c < 8; c++){
      float4 v0 = *(const float4*)(q + c * 8);
      float4 v1 = *(const float4*)(q + c * 8 + 4);
      bf16x8 o;
      o[0] = f2bf(v0.x); o[1] = f2bf(v0.y); o[2] = f2bf(v0.z); o[3] = f2bf(v0.w);
      o[4] = f2bf(v1.x); o[5] = f2bf(v1.y); o[6] = f2bf(v1.z); o[7] = f2bf(v1.w);
      *(bf16x8*)(qo + c * 8) = o;
      #pragma unroll
      for (int e = 0; e < 8; e++){
        const float* w = gw + e * 64 + c * 8;     // uniform -> s_load
        g[e] += v0.x * w[0] + v0.y * w[1] + v0.z * w[2] + v0.w * w[3]
              + v1.x * w[4] + v1.y * w[5] + v1.z * w[6] + v1.w * w[7];
      }
    }
    float a0 = (g[0] + g[1]) + (g[2] + g[3]);
    float a1 = (g[4] + g[5]) + (g[6] + g[7]);
    float sa = 1.f / (1.f + __expf(-a0));
    float sb = 1.f / (1.f + __expf(-a1));
    gates[bh * T_ + t] = (sa * (sb * ga[h] - 1.0f) + 2.0f) * LOG2E;   // pre-scaled for exp2
  } else {
    int tb = bid - 4352;               // 0..127
    int h = tb >> 3;
    int i = (tb & 7) * 256 + tid;
    if (i < 2047){
      int rp = i - 1023;
      int base = rp > 0 ? 16 : 0;
      int arp = rp < 0 ? -rp : rp;
      int off;
      if (arp < 8) off = arp;
      else {
        float val = (logf((float)arp * 0.125f) / 2.772588722239781f) * 8.0f;
        int lg = (int)val;
        off = 8 + (lg > 7 ? 7 : lg);
      }
      tab[h * 2047 + i] = rel_bias[(base + off) * H_ + h];   // fp32
    }
  }
}

// ---------------- fused QKV GEMM: one block = 128 m-rows x 64 n-cols x {q,k,v} ----------------
__global__ __launch_bounds__(256, 2) void gemm_qkv(
    const __bf16* __restrict__ A,
    const __bf16* __restrict__ W0, const __bf16* __restrict__ W1, const __bf16* __restrict__ W2,
    const float* __restrict__ b0, const float* __restrict__ b1, const float* __restrict__ b2,
    __bf16* out0, __bf16* out1, __bf16* out2)
{
  __shared__ __bf16 As[128 * 64];      // 16 KB; reused as v-transpose buffer in epilogue
  __shared__ __bf16 Bs[3][64 * 64];    // 3 x 8 KB
  const int tid = threadIdx.x;
  const int lane = tid & 63, wid = tid >> 6;
  const int l15 = lane & 15, quad = lane >> 4;
  const int dd = blockIdx.x;
  const int j = dd >> 3;
  const int m0 = ((dd & 7) * 4 + (j & 3)) * 128;   // m fast within XCD -> A-slab reuse
  const int nt = j >> 2;                            // 0..15 = head index
  const int n0 = nt * 64;

  f32x4 acc[3][2][4];
  #pragma unroll
  for (int z = 0; z < 3; z++)
    #pragma unroll
    for (int i = 0; i < 2; i++)
      #pragma unroll
      for (int jj = 0; jj < 4; jj++){
        acc[z][i][jj][0] = 0.f; acc[z][i][jj][1] = 0.f;
        acc[z][i][jj][2] = 0.f; acc[z][i][jj][3] = 0.f;
      }

  const int grow = lane >> 3;
  const int gcol = (((lane & 7) ^ grow) * 8);
  const int sw = (l15 & 7);

  for (int k0 = 0; k0 < E_; k0 += 64){
    __syncthreads();
    #pragma unroll
    for (int r = 0; r < 4; r++){
      int rb = wid * 32 + r * 8;
      glds16(A + (size_t)(m0 + rb + grow) * E_ + k0 + gcol, &As[rb * 64]);
    }
    #pragma unroll
    for (int r = 0; r < 2; r++){
      int rb = wid * 16 + r * 8;
      glds16(W0 + (size_t)(n0 + rb + grow) * E_ + k0 + gcol, &Bs[0][rb * 64]);
      glds16(W1 + (size_t)(n0 + rb + grow) * E_ + k0 + gcol, &Bs[1][rb * 64]);
      glds16(W2 + (size_t)(n0 + rb + grow) * E_ + k0 + gcol, &Bs[2][rb * 64]);
    }
    __syncthreads();
    #pragma unroll
    for (int kq = 0; kq < 2; kq++){
      const int ce = ((kq * 4 + quad) ^ sw) * 8;
      bf16x8 am[2];
      #pragma unroll
      for (int i = 0; i < 2; i++) am[i] = *(const bf16x8*)&As[(wid * 32 + i * 16 + l15) * 64 + ce];
      #pragma unroll
      for (int z = 0; z < 3; z++){
        bf16x8 bn[4];
        #pragma unroll
        for (int jj = 0; jj < 4; jj++) bn[jj] = *(const bf16x8*)&Bs[z][(jj * 16 + l15) * 64 + ce];
        #pragma unroll
        for (int i = 0; i < 2; i++)
          #pragma unroll
          for (int jj = 0; jj < 4; jj++)
            acc[z][i][jj] = __builtin_amdgcn_mfma_f32_16x16x32_bf16(am[i], bn[jj], acc[z][i][jj], 0, 0, 0);
      }
    }
  }

  #pragma unroll
  for (int z = 0; z < 2; z++){
    __bf16* outp = z ? out1 : out0;
    const float* bias = z ? b1 : b0;
    const float scale = z ? 1.0f : 0.125f * LOG2E;
    #pragma unroll
    for (int i = 0; i < 2; i++){
      const int row0 = m0 + wid * 32 + i * 16 + quad * 4;
      #pragma unroll
      for (int jj = 0; jj < 4; jj++){
        const int col = n0 + jj * 16 + l15;
        const float bc = bias[col];
        const int d2 = col & 63;
        #pragma unroll
        for (int r = 0; r < 4; r++){
          float v = (acc[z][i][jj][r] + bc) * scale;
          int row = row0 + r;
          int t = row >> 2, bb = row & 3;
          outp[(size_t)((bb * H_ + nt) * T_ + t) * DH_ + d2] = f2bf(v);
        }
      }
    }
  }

  __syncthreads();
  __bf16 (*vbuf)[4][32] = (__bf16 (*)[4][32])&As[0];
  #pragma unroll
  for (int i = 0; i < 2; i++){
    const int t_local = wid * 8 + i * 4 + quad;
    #pragma unroll
    for (int jj = 0; jj < 4; jj++){
      const int nl = jj * 16 + l15;
      const float bc = b2[n0 + nl];
      #pragma unroll
      for (int r = 0; r < 4; r++)
        vbuf[nl][r][t_local] = f2bf(acc[2][i][jj][r] + bc);
    }
  }
  __syncthreads();
  {
    const int nl = tid >> 2;
    const int bb = tid & 3;
    __bf16* dst = out2 + (size_t)((bb * H_ + nt) * DH_ + nl) * T_ + (m0 >> 2);
    const __bf16* src = &vbuf[nl][bb][0];
    #pragma unroll
    for (int c = 0; c < 4; c++)
      *(bf16x8*)(dst + c * 8) = *(const bf16x8*)(src + c * 8);
  }
}

// ---------------- out-proj GEMM: 64x128 tile, BK=64, XOR-swizzled LDS, XCD grid (512), fp32 write ----------------
__global__ __launch_bounds__(256) void gemm_out(
    const __bf16* __restrict__ A, const __bf16* __restrict__ W,
    const float* __restrict__ bias, float* __restrict__ out)
{
  __shared__ __bf16 As[64 * 64];
  __shared__ __bf16 Bs[128 * 64];
  const int tid = threadIdx.x;
  const int lane = tid & 63, wid = tid >> 6;
  const int l15 = lane & 15, quad = lane >> 4;
  const int wm = wid >> 1, wn = wid & 1;
  const int dd = blockIdx.x;
  const int j = dd >> 3;
  const int m0 = ((dd & 7) * 8 + (j & 7)) * 64;
  const int n0 = (j >> 3) * 128;

  f32x4 acc[2][4];
  #pragma unroll
  for (int i = 0; i < 2; i++)
    #pragma unroll
    for (int jj = 0; jj < 4; jj++){
      acc[i][jj][0] = 0.f; acc[i][jj][1] = 0.f; acc[i][jj][2] = 0.f; acc[i][jj][3] = 0.f;
    }

  const int grow = lane >> 3;
  const int gcol = (((lane & 7) ^ grow) * 8);
  const int sw = (l15 & 7);

  for (int k0 = 0; k0 < E_; k0 += 64){
    __syncthreads();
    #pragma unroll
    for (int r = 0; r < 2; r++){
      int rbA = wid * 16 + r * 8;
      glds16(A + (size_t)(m0 + rbA + grow) * E_ + k0 + gcol, &As[rbA * 64]);
    }
    #pragma unroll
    for (int r = 0; r < 4; r++){
      int rbB = wid * 32 + r * 8;
      glds16(W + (size_t)(n0 + rbB + grow) * E_ + k0 + gcol, &Bs[rbB * 64]);
    }
    __syncthreads();
    #pragma unroll
    for (int kq = 0; kq < 2; kq++){
      const int ce = ((kq * 4 + quad) ^ sw) * 8;
      bf16x8 am[2], bn[4];
      #pragma unroll
      for (int i = 0; i < 2; i++) am[i] = *(const bf16x8*)&As[(wm * 32 + i * 16 + l15) * 64 + ce];
      #pragma unroll
      for (int jj = 0; jj < 4; jj++) bn[jj] = *(const bf16x8*)&Bs[(wn * 64 + jj * 16 + l15) * 64 + ce];
      #pragma unroll
      for (int i = 0; i < 2; i++)
        #pragma unroll
        for (int jj = 0; jj < 4; jj++)
          acc[i][jj] = __builtin_amdgcn_mfma_f32_16x16x32_bf16(am[i], bn[jj], acc[i][jj], 0, 0, 0);
    }
  }

  #pragma unroll
  for (int i = 0; i < 2; i++){
    const int row0 = m0 + wm * 32 + i * 16 + quad * 4;
    #pragma unroll
    for (int jj = 0; jj < 4; jj++){
      const int col = n0 + wn * 64 + jj * 16 + l15;
      const float bc = bias[col];
      #pragma unroll
      for (int r = 0; r < 4; r++)
        out[(size_t)(row0 + r) * E_ + col] = acc[i][jj][r] + bc;
    }
  }
}

// ---------------- flash attention v7: no K/V LDS — direct coalesced global fragment loads ----------------
// 2048 blocks x 64 threads (1 wave, 32 t = 2 t-groups). K frag ak[nt]: 16B/lane contiguous from
// (B,H,T,DH); V frag av[mt]: 16B/lane contiguous from (B,H,DH,T). LDS only for P round-trip +
// tab window (6.5 KB). __launch_bounds__(64,2) caps VGPR at 256 -> 2 waves/SIMD, 8 blocks/CU.
// Software pipeline: S(ak) -> issue ak' -> exp2/P -> PV(av) -> issue av'; per-register vmcnt
// gives each load ~a full phase of latency cover.
__global__ __launch_bounds__(64, 2) void attn_kernel(
    const __bf16* __restrict__ qg, const __bf16* __restrict__ kg, const __bf16* __restrict__ vgT,
    const float* __restrict__ gates, const float* __restrict__ tab,
    __bf16* __restrict__ ctx)
{
  __shared__ __bf16 Pt[2][16 * 72];    // per-t-group P^T buffers
  __shared__ float tabh[512];          // rel-bias window rp in [-255,256] (index rp+255)

  const int lane = threadIdx.x;        // single wave
  const int l15 = lane & 15, quad = lane >> 4;
  // XCD swizzle: all 32 t-blocks of a bh share XCD slot dgrid&7
  const int dgrid = blockIdx.x;
  const int j = dgrid >> 3;
  const int bh = (dgrid & 7) + 8 * (j & 7);
  const int tq = j >> 3;               // 0..31 -> t-base tq*32
  const int b = bh >> 4, h = bh & 15;
  const __bf16* qb = qg + (size_t)bh * T_ * DH_;
  const __bf16* kb = kg + (size_t)bh * T_ * DH_;
  const __bf16* vb = vgT + (size_t)bh * DH_ * T_;

  #pragma unroll
  for (int i = 0; i < 8; i++) tabh[i * 64 + lane] = tab[h * 2047 + 768 + i * 64 + lane];

  const int t0w = tq * 32;
  bf16x8 bq[2][2];
  float g[2];
  #pragma unroll
  for (int tg = 0; tg < 2; tg++){
    int t_lane = t0w + tg * 16 + l15;
    bq[tg][0] = *(const bf16x8*)(qb + (size_t)t_lane * DH_ + quad * 8);
    bq[tg][1] = *(const bf16x8*)(qb + (size_t)t_lane * DH_ + 32 + quad * 8);
    g[tg] = gates[bh * T_ + t_lane];   // already * log2e
  }

  // fragment base pointers (16B/lane contiguous)
  const __bf16* kfrag = kb + (size_t)l15 * DH_ + quad * 8;   // + (s0+nt*16)*DH + ks*32
  const __bf16* vfrag = vb + (size_t)l15 * T_ + quad * 8;    // + (mt*16)*T + s0 + ks*32

  float l_run[2] = {0.f, 0.f};
  f32x4 O[2][4];
  #pragma unroll
  for (int tg = 0; tg < 2; tg++)
    #pragma unroll
    for (int mt = 0; mt < 4; mt++){ O[tg][mt][0]=0.f; O[tg][mt][1]=0.f; O[tg][mt][2]=0.f; O[tg][mt][3]=0.f; }

  // prologue: load tile-0 K and V fragments
  bf16x8 ak[4][2], av[4][2];
  #pragma unroll
  for (int nt = 0; nt < 4; nt++){
    ak[nt][0] = *(const bf16x8*)(kfrag + (size_t)(nt * 16) * DH_);
    ak[nt][1] = *(const bf16x8*)(kfrag + (size_t)(nt * 16) * DH_ + 32);
    av[nt][0] = *(const bf16x8*)(vfrag + (size_t)(nt * 16) * T_);
    av[nt][1] = *(const bf16x8*)(vfrag + (size_t)(nt * 16) * T_ + 32);
  }

  for (int s0 = 0; s0 < T_; s0 += 64){
    // ---- phase 1: S^T = K.Q^T (consumes ak) ----
    f32x4 S[2][4];
    #pragma unroll
    for (int nt = 0; nt < 4; nt++){
      #pragma unroll
      for (int tg = 0; tg < 2; tg++){
        f32x4 a; a[0]=0.f; a[1]=0.f; a[2]=0.f; a[3]=0.f;
        a = __builtin_amdgcn_mfma_f32_16x16x32_bf16(ak[nt][0], bq[tg][0], a, 0, 0, 0);
        a = __builtin_amdgcn_mfma_f32_16x16x32_bf16(ak[nt][1], bq[tg][1], a, 0, 0, 0);
        S[tg][nt] = a;
      }
    }

    // ---- phase 2: prefetch next-tile K fragments (ak regs reusable after MFMA issue) ----
    const int sn = (s0 + 64) & (T_ - 1);   // wraps at tail; extra loads discarded
    #pragma unroll
    for (int nt = 0; nt < 4; nt++){
      ak[nt][0] = *(const bf16x8*)(kfrag + (size_t)(sn + nt * 16) * DH_);
      ak[nt][1] = *(const bf16x8*)(kfrag + (size_t)(sn + nt * 16) * DH_ + 32);
    }

    // ---- phase 3: bias + exp2 + P write + denominator ----
    const int drel = s0 - t0w;
    const bool sat = (drel >= 160) || (drel <= -192);      // exact T5 bucket clamp
    const float svc = (drel > 0) ? tabh[383] : tabh[127];  // rp=+128 / rp=-128 values
    #pragma unroll
    for (int tg = 0; tg < 2; tg++){
      if (sat){
        const float cb = g[tg] * svc;
        #pragma unroll
        for (int nt = 0; nt < 4; nt++)
          #pragma unroll
          for (int r = 0; r < 4; r++)
            S[tg][nt][r] = __builtin_amdgcn_exp2f(S[tg][nt][r] + cb);
      } else {
        const int ib = drel + 255 - tg * 16 - l15;
        #pragma unroll
        for (int nt = 0; nt < 4; nt++)
          #pragma unroll
          for (int r = 0; r < 4; r++)
            S[tg][nt][r] = __builtin_amdgcn_exp2f(S[tg][nt][r] + g[tg] * tabh[ib + nt * 16 + quad * 4 + r]);
      }
      __bf16* pw = &Pt[tg][0];
      #pragma unroll
      for (int nt = 0; nt < 4; nt++){
        bf16x4 p;
        p[0] = f2bf_fast(S[tg][nt][0]); p[1] = f2bf_fast(S[tg][nt][1]);
        p[2] = f2bf_fast(S[tg][nt][2]); p[3] = f2bf_fast(S[tg][nt][3]);
        *(bf16x4*)&pw[l15 * 72 + nt * 16 + quad * 4] = p;
      }
      float rs = 0.f;
      #pragma unroll
      for (int nt = 0; nt < 4; nt++) rs += (S[tg][nt][0] + S[tg][nt][1]) + (S[tg][nt][2] + S[tg][nt][3]);
      rs += __shfl_xor(rs, 16, 64);
      rs += __shfl_xor(rs, 32, 64);
      l_run[tg] += rs;
    }

    // ---- phase 4: O^T += V^T.P^T (consumes av; P read back from wave-local LDS) ----
    #pragma unroll
    for (int ks = 0; ks < 2; ks++){
      bf16x8 bp[2];
      #pragma unroll
      for (int tg = 0; tg < 2; tg++)
        bp[tg] = *(const bf16x8*)&Pt[tg][l15 * 72 + ks * 32 + quad * 8];
      #pragma unroll
      for (int mt = 0; mt < 4; mt++)
        #pragma unroll
        for (int tg = 0; tg < 2; tg++)
          O[tg][mt] = __builtin_amdgcn_mfma_f32_16x16x32_bf16(av[mt][ks], bp[tg], O[tg][mt], 0, 0, 0);
    }

    // ---- phase 5: prefetch next-tile V fragments (waited at next iter's phase 4) ----
    #pragma unroll
    for (int mt = 0; mt < 4; mt++){
      av[mt][0] = *(const bf16x8*)(vfrag + (size_t)(mt * 16) * T_ + sn);
      av[mt][1] = *(const bf16x8*)(vfrag + (size_t)(mt * 16) * T_ + sn + 32);
    }
  }

  // epilogue: ctx[(t*B+b)*E + h*64+d], d = mt*16+quad*4+r
  #pragma unroll
  for (int tg = 0; tg < 2; tg++){
    const int t_lane = t0w + tg * 16 + l15;
    const float inv = 1.f / l_run[tg];
    #pragma unroll
    for (int mt = 0; mt < 4; mt++){
      bf16x4 o;
      o[0] = f2bf(O[tg][mt][0] * inv); o[1] = f2bf(O[tg][mt][1] * inv);
      o[2] = f2bf(O[tg][mt][2] * inv); o[3] = f2bf(O[tg][mt][3] * inv);
      *(bf16x4*)&ctx[(size_t)(t_lane * B_ + b) * E_ + h * DH_ + mt * 16 + quad * 4] = o;
    }
  }
}

extern "C" void kernel_launch(void* const* d_in, const int* in_sizes, int n_in,
                              void* d_out, int out_size, void* d_ws, size_t ws_size,
                              hipStream_t stream)
{
  (void)in_sizes; (void)n_in; (void)out_size; (void)ws_size;
  const float* query    = (const float*)d_in[0];
  const float* q_w      = (const float*)d_in[1];
  const float* q_b      = (const float*)d_in[2];
  const float* k_w      = (const float*)d_in[3];
  const float* k_b      = (const float*)d_in[4];
  const float* v_w      = (const float*)d_in[5];
  const float* v_b      = (const float*)d_in[6];
  const float* out_w    = (const float*)d_in[7];
  const float* out_b    = (const float*)d_in[8];
  const float* rel_bias = (const float*)d_in[9];
  const float* grep_w   = (const float*)d_in[10];
  const float* grep_b   = (const float*)d_in[11];
  const float* grep_a   = (const float*)d_in[12];

  char* ws = (char*)d_ws;
  size_t off = 0;
  __bf16* qbf = (__bf16*)(ws + off); off += (size_t)4096 * 1024 * 2;   // query bf16 (TB, E)
  __bf16* wq  = (__bf16*)(ws + off); off += (size_t)1024 * 1024 * 2;
  __bf16* wk  = (__bf16*)(ws + off); off += (size_t)1024 * 1024 * 2;
  __bf16* wv  = (__bf16*)(ws + off); off += (size_t)1024 * 1024 * 2;
  __bf16* wo  = (__bf16*)(ws + off); off += (size_t)1024 * 1024 * 2;
  __bf16* qh  = (__bf16*)(ws + off); off += (size_t)4096 * 1024 * 2;   // (B,H,T,DH)
  __bf16* kh  = (__bf16*)(ws + off); off += (size_t)4096 * 1024 * 2;   // (B,H,T,DH)
  __bf16* vhT = (__bf16*)(ws + off); off += (size_t)4096 * 1024 * 2;   // (B,H,DH,T)
  __bf16* ctx = (__bf16*)(ws + off); off += (size_t)4096 * 1024 * 2;   // (TB, E)
  float* gates = (float*)(ws + off); off += (size_t)65536 * 4;         // (B*H, T), * log2e
  float* tab   = (float*)(ws + off); off += (size_t)16 * 2047 * 4;     // (H, 2047) fp32

  prep_kernel<<<4480, 256, 0, stream>>>(q_w, k_w, v_w, out_w, wq, wk, wv, wo,
                                        query, grep_w, grep_b, grep_a, gates, qbf,
                                        rel_bias, tab);
  gemm_qkv<<<512, 256, 0, stream>>>(qbf, wq, wk, wv, q_b, k_b, v_b, qh, kh, vhT);
  attn_kernel<<<2048, 64, 0, stream>>>(qh, kh, vhT, gates, tab, ctx);
  gemm_out<<<512, 256, 0, stream>>>(ctx, wo, out_b, (float*)d_out);
}

// Round 11
// 200.496 us; speedup vs baseline: 1.1512x; 1.1512x over previous
//
#include <hip/hip_runtime.h>
#include <math.h>

// Problem constants (reference: T,B,E,H = 1024,4,1024,16; DH=64; 32 buckets, max_dist 128)
#define T_ 1024
#define B_ 4
#define E_ 1024
#define H_ 16
#define DH_ 64

#define LOG2E 1.44269504088896f

typedef __attribute__((ext_vector_type(8))) __bf16 bf16x8;
typedef __attribute__((ext_vector_type(4))) __bf16 bf16x4;
typedef __attribute__((ext_vector_type(4))) float f32x4;

// fp32 -> bf16 round-to-nearest-even
__device__ __forceinline__ __bf16 f2bf(float x){
  union { unsigned short u; __bf16 b; } cv;
  unsigned u32 = __float_as_uint(x);
  cv.u = (unsigned short)((u32 + 0x7fffu + ((u32 >> 16) & 1u)) >> 16);
  return cv.b;
}
// fp32 -> bf16 round-half-up (cheaper; used only for P >= 0)
__device__ __forceinline__ __bf16 f2bf_fast(float x){
  union { unsigned short u; __bf16 b; } cv;
  cv.u = (unsigned short)((__float_as_uint(x) + 0x8000u) >> 16);
  return cv.b;
}

// async global->LDS, 16B per lane; LDS dest is wave-uniform base + lane*16 (m97/m104)
__device__ __forceinline__ void glds16(const void* g, void* l){
  __builtin_amdgcn_global_load_lds(
      (__attribute__((address_space(1))) void*)(void*)g,
      (__attribute__((address_space(3))) void*)l,
      16, 0, 0);
}

// ---------------- prep: weight cvt (blocks 0..4095) + gates/qbf (4096..4351) + tab (4352..4479) ----------------
__global__ __launch_bounds__(256) void prep_kernel(
    const float* __restrict__ q_w, const float* __restrict__ k_w,
    const float* __restrict__ v_w, const float* __restrict__ out_w,
    __bf16* __restrict__ wq, __bf16* __restrict__ wk,
    __bf16* __restrict__ wv, __bf16* __restrict__ wo,
    const float* __restrict__ query, const float* __restrict__ gw,
    const float* __restrict__ gb, const float* __restrict__ ga,
    float* __restrict__ gates, __bf16* __restrict__ qbf,
    const float* __restrict__ rel_bias, float* __restrict__ tab)
{
  const int bid = blockIdx.x;
  const int tid = threadIdx.x;
  if (bid < 4096){
    const float* a; __bf16* o;
    switch (bid >> 10){
      case 0: a = q_w;  o = wq; break;
      case 1: a = k_w;  o = wk; break;
      case 2: a = v_w;  o = wv; break;
      default: a = out_w; o = wo; break;
    }
    int i = ((bid & 1023) * 256 + tid) * 4;
    float4 v = *(const float4*)(a + i);
    bf16x4 r;
    r[0] = f2bf(v.x); r[1] = f2bf(v.y); r[2] = f2bf(v.z); r[3] = f2bf(v.w);
    *(bf16x4*)(o + i) = r;
  } else if (bid < 4352){
    int t = (bid - 4096) * 4 + (tid >> 6);
    int bh = tid & 63;
    int h = bh & 15;
    const float* q = query + (size_t)t * E_ * B_ + bh * 64;
    __bf16* qo = qbf + (size_t)t * E_ * B_ + bh * 64;
    float g[8];
    #pragma unroll
    for (int e = 0; e < 8; e++) g[e] = gb[e];
    #pragma unroll
    for (int c = 0; c < 8; c++){
      float4 v0 = *(const float4*)(q + c * 8);
      float4 v1 = *(const float4*)(q + c * 8 + 4);
      bf16x8 o;
      o[0] = f2bf(v0.x); o[1] = f2bf(v0.y); o[2] = f2bf(v0.z); o[3] = f2bf(v0.w);
      o[4] = f2bf(v1.x); o[5] = f2bf(v1.y); o[6] = f2bf(v1.z); o[7] = f2bf(v1.w);
      *(bf16x8*)(qo + c * 8) = o;
      #pragma unroll
      for (int e = 0; e < 8; e++){
        const float* w = gw + e * 64 + c * 8;     // uniform -> s_load
        g[e] += v0.x * w[0] + v0.y * w[1] + v0.z * w[2] + v0.w * w[3]
              + v1.x * w[4] + v1.y * w[5] + v1.z * w[6] + v1.w * w[7];
      }
    }
    float a0 = (g[0] + g[1]) + (g[2] + g[3]);
    float a1 = (g[4] + g[5]) + (g[6] + g[7]);
    float sa = 1.f / (1.f + __expf(-a0));
    float sb = 1.f / (1.f + __expf(-a1));
    gates[bh * T_ + t] = (sa * (sb * ga[h] - 1.0f) + 2.0f) * LOG2E;   // pre-scaled for exp2
  } else {
    int tb = bid - 4352;               // 0..127
    int h = tb >> 3;
    int i = (tb & 7) * 256 + tid;
    if (i < 2047){
      int rp = i - 1023;
      int base = rp > 0 ? 16 : 0;
      int arp = rp < 0 ? -rp : rp;
      int off;
      if (arp < 8) off = arp;
      else {
        float val = (logf((float)arp * 0.125f) / 2.772588722239781f) * 8.0f;
        int lg = (int)val;
        off = 8 + (lg > 7 ? 7 : lg);
      }
      tab[h * 2047 + i] = rel_bias[(base + off) * H_ + h];   // fp32
    }
  }
}

// ---------------- fused QKV GEMM: one block = 128 m-rows x 64 n-cols x {q,k,v} ----------------
__global__ __launch_bounds__(256, 2) void gemm_qkv(
    const __bf16* __restrict__ A,
    const __bf16* __restrict__ W0, const __bf16* __restrict__ W1, const __bf16* __restrict__ W2,
    const float* __restrict__ b0, const float* __restrict__ b1, const float* __restrict__ b2,
    __bf16* out0, __bf16* out1, __bf16* out2)
{
  __shared__ __bf16 As[128 * 64];      // 16 KB; reused as v-transpose buffer in epilogue
  __shared__ __bf16 Bs[3][64 * 64];    // 3 x 8 KB
  const int tid = threadIdx.x;
  const int lane = tid & 63, wid = tid >> 6;
  const int l15 = lane & 15, quad = lane >> 4;
  const int dd = blockIdx.x;
  const int j = dd >> 3;
  const int m0 = ((dd & 7) * 4 + (j & 3)) * 128;   // m fast within XCD -> A-slab reuse
  const int nt = j >> 2;                            // 0..15 = head index
  const int n0 = nt * 64;

  f32x4 acc[3][2][4];
  #pragma unroll
  for (int z = 0; z < 3; z++)
    #pragma unroll
    for (int i = 0; i < 2; i++)
      #pragma unroll
      for (int jj = 0; jj < 4; jj++){
        acc[z][i][jj][0] = 0.f; acc[z][i][jj][1] = 0.f;
        acc[z][i][jj][2] = 0.f; acc[z][i][jj][3] = 0.f;
      }

  const int grow = lane >> 3;
  const int gcol = (((lane & 7) ^ grow) * 8);
  const int sw = (l15 & 7);

  for (int k0 = 0; k0 < E_; k0 += 64){
    __syncthreads();
    #pragma unroll
    for (int r = 0; r < 4; r++){
      int rb = wid * 32 + r * 8;
      glds16(A + (size_t)(m0 + rb + grow) * E_ + k0 + gcol, &As[rb * 64]);
    }
    #pragma unroll
    for (int r = 0; r < 2; r++){
      int rb = wid * 16 + r * 8;
      glds16(W0 + (size_t)(n0 + rb + grow) * E_ + k0 + gcol, &Bs[0][rb * 64]);
      glds16(W1 + (size_t)(n0 + rb + grow) * E_ + k0 + gcol, &Bs[1][rb * 64]);
      glds16(W2 + (size_t)(n0 + rb + grow) * E_ + k0 + gcol, &Bs[2][rb * 64]);
    }
    __syncthreads();
    #pragma unroll
    for (int kq = 0; kq < 2; kq++){
      const int ce = ((kq * 4 + quad) ^ sw) * 8;
      bf16x8 am[2];
      #pragma unroll
      for (int i = 0; i < 2; i++) am[i] = *(const bf16x8*)&As[(wid * 32 + i * 16 + l15) * 64 + ce];
      #pragma unroll
      for (int z = 0; z < 3; z++){
        bf16x8 bn[4];
        #pragma unroll
        for (int jj = 0; jj < 4; jj++) bn[jj] = *(const bf16x8*)&Bs[z][(jj * 16 + l15) * 64 + ce];
        #pragma unroll
        for (int i = 0; i < 2; i++)
          #pragma unroll
          for (int jj = 0; jj < 4; jj++)
            acc[z][i][jj] = __builtin_amdgcn_mfma_f32_16x16x32_bf16(am[i], bn[jj], acc[z][i][jj], 0, 0, 0);
      }
    }
  }

  #pragma unroll
  for (int z = 0; z < 2; z++){
    __bf16* outp = z ? out1 : out0;
    const float* bias = z ? b1 : b0;
    const float scale = z ? 1.0f : 0.125f * LOG2E;
    #pragma unroll
    for (int i = 0; i < 2; i++){
      const int row0 = m0 + wid * 32 + i * 16 + quad * 4;
      #pragma unroll
      for (int jj = 0; jj < 4; jj++){
        const int col = n0 + jj * 16 + l15;
        const float bc = bias[col];
        const int d2 = col & 63;
        #pragma unroll
        for (int r = 0; r < 4; r++){
          float v = (acc[z][i][jj][r] + bc) * scale;
          int row = row0 + r;
          int t = row >> 2, bb = row & 3;
          outp[(size_t)((bb * H_ + nt) * T_ + t) * DH_ + d2] = f2bf(v);
        }
      }
    }
  }

  __syncthreads();
  __bf16 (*vbuf)[4][32] = (__bf16 (*)[4][32])&As[0];
  #pragma unroll
  for (int i = 0; i < 2; i++){
    const int t_local = wid * 8 + i * 4 + quad;
    #pragma unroll
    for (int jj = 0; jj < 4; jj++){
      const int nl = jj * 16 + l15;
      const float bc = b2[n0 + nl];
      #pragma unroll
      for (int r = 0; r < 4; r++)
        vbuf[nl][r][t_local] = f2bf(acc[2][i][jj][r] + bc);
    }
  }
  __syncthreads();
  {
    const int nl = tid >> 2;
    const int bb = tid & 3;
    __bf16* dst = out2 + (size_t)((bb * H_ + nt) * DH_ + nl) * T_ + (m0 >> 2);
    const __bf16* src = &vbuf[nl][bb][0];
    #pragma unroll
    for (int c = 0; c < 4; c++)
      *(bf16x8*)(dst + c * 8) = *(const bf16x8*)(src + c * 8);
  }
}

// ---------------- out-proj GEMM: 64x128 tile, BK=64, XOR-swizzled LDS, XCD grid (512), fp32 write ----------------
__global__ __launch_bounds__(256) void gemm_out(
    const __bf16* __restrict__ A, const __bf16* __restrict__ W,
    const float* __restrict__ bias, float* __restrict__ out)
{
  __shared__ __bf16 As[64 * 64];
  __shared__ __bf16 Bs[128 * 64];
  const int tid = threadIdx.x;
  const int lane = tid & 63, wid = tid >> 6;
  const int l15 = lane & 15, quad = lane >> 4;
  const int wm = wid >> 1, wn = wid & 1;
  const int dd = blockIdx.x;
  const int j = dd >> 3;
  const int m0 = ((dd & 7) * 8 + (j & 7)) * 64;
  const int n0 = (j >> 3) * 128;

  f32x4 acc[2][4];
  #pragma unroll
  for (int i = 0; i < 2; i++)
    #pragma unroll
    for (int jj = 0; jj < 4; jj++){
      acc[i][jj][0] = 0.f; acc[i][jj][1] = 0.f; acc[i][jj][2] = 0.f; acc[i][jj][3] = 0.f;
    }

  const int grow = lane >> 3;
  const int gcol = (((lane & 7) ^ grow) * 8);
  const int sw = (l15 & 7);

  for (int k0 = 0; k0 < E_; k0 += 64){
    __syncthreads();
    #pragma unroll
    for (int r = 0; r < 2; r++){
      int rbA = wid * 16 + r * 8;
      glds16(A + (size_t)(m0 + rbA + grow) * E_ + k0 + gcol, &As[rbA * 64]);
    }
    #pragma unroll
    for (int r = 0; r < 4; r++){
      int rbB = wid * 32 + r * 8;
      glds16(W + (size_t)(n0 + rbB + grow) * E_ + k0 + gcol, &Bs[rbB * 64]);
    }
    __syncthreads();
    #pragma unroll
    for (int kq = 0; kq < 2; kq++){
      const int ce = ((kq * 4 + quad) ^ sw) * 8;
      bf16x8 am[2], bn[4];
      #pragma unroll
      for (int i = 0; i < 2; i++) am[i] = *(const bf16x8*)&As[(wm * 32 + i * 16 + l15) * 64 + ce];
      #pragma unroll
      for (int jj = 0; jj < 4; jj++) bn[jj] = *(const bf16x8*)&Bs[(wn * 64 + jj * 16 + l15) * 64 + ce];
      #pragma unroll
      for (int i = 0; i < 2; i++)
        #pragma unroll
        for (int jj = 0; jj < 4; jj++)
          acc[i][jj] = __builtin_amdgcn_mfma_f32_16x16x32_bf16(am[i], bn[jj], acc[i][jj], 0, 0, 0);
    }
  }

  #pragma unroll
  for (int i = 0; i < 2; i++){
    const int row0 = m0 + wm * 32 + i * 16 + quad * 4;
    #pragma unroll
    for (int jj = 0; jj < 4; jj++){
      const int col = n0 + wn * 64 + jj * 16 + l15;
      const float bc = bias[col];
      #pragma unroll
      for (int r = 0; r < 4; r++)
        out[(size_t)(row0 + r) * E_ + col] = acc[i][jj][r] + bc;
    }
  }
}

// ---------------- flash attention v5b: 64 t per block, 128 thr (2 waves), 5 blocks/CU ----------------
// Round-8 structure (best measured) with the tab LDS shrunk to a 512-entry window (2 KB):
// non-saturated tiles only touch rp in [-191,191]; saturated tiles use the exact T5 clamp
// constants at rp=+/-128. LDS 27.6 KB -> 5 blocks/CU (was 4) for +25% resident waves.
__global__ __launch_bounds__(128) void attn_kernel(
    const __bf16* __restrict__ qg, const __bf16* __restrict__ kg, const __bf16* __restrict__ vgT,
    const float* __restrict__ gates, const float* __restrict__ tab,
    __bf16* __restrict__ ctx)
{
  const int LDP = 72;
  __shared__ __bf16 Ks[64 * 64];       // 8 KB, XOR-swizzled chunks: slot c holds chunk c^(row&7)
  __shared__ __bf16 Vt[64 * 64];       // 8 KB, same (rows = d, cols = s)
  __shared__ __bf16 Pt[2][2][16 * LDP];// 9 KB, per-(wave, tg) P^T
  __shared__ float tabh[512];          // 2 KB, rel-bias window rp in [-255,256] (index rp+255)

  const int tid = threadIdx.x;
  const int lane = tid & 63, wid = tid >> 6;       // 2 waves
  const int l15 = lane & 15, quad = lane >> 4;
  // XCD swizzle: all 16 t-blocks of a bh share XCD slot dgrid&7
  const int dgrid = blockIdx.x;
  const int j = dgrid >> 3;
  const int bh = (dgrid & 7) + 8 * (j & 7);
  const int tq = j >> 3;               // 0..15 -> t-base tq*64
  const int b = bh >> 4, h = bh & 15;
  const __bf16* qb = qg + (size_t)bh * T_ * DH_;
  const __bf16* kb = kg + (size_t)bh * T_ * DH_;
  const __bf16* vb = vgT + (size_t)bh * DH_ * T_;

  #pragma unroll
  for (int i = 0; i < 4; i++) tabh[i * 128 + tid] = tab[h * 2047 + 768 + i * 128 + tid];

  const int t0w = tq * 64 + wid * 32;  // wave owns 32 t = 2 groups of 16
  bf16x8 bq[2][2];
  float g[2];
  #pragma unroll
  for (int tg = 0; tg < 2; tg++){
    int t_lane = t0w + tg * 16 + l15;
    bq[tg][0] = *(const bf16x8*)(qb + (size_t)t_lane * DH_ + quad * 8);
    bq[tg][1] = *(const bf16x8*)(qb + (size_t)t_lane * DH_ + 32 + quad * 8);
    g[tg] = gates[bh * T_ + t_lane];   // already * log2e
  }

  const int grow = lane >> 3;                  // staging row within 8-row group
  const int gcol = (((lane & 7) ^ grow) * 8);  // XOR-swizzled source chunk
  const int swf = (l15 & 7);                   // frag-read swizzle key

  float l_run[2] = {0.f, 0.f};
  f32x4 O[2][4];
  #pragma unroll
  for (int tg = 0; tg < 2; tg++)
    #pragma unroll
    for (int mt = 0; mt < 4; mt++){ O[tg][mt][0]=0.f; O[tg][mt][1]=0.f; O[tg][mt][2]=0.f; O[tg][mt][3]=0.f; }

  for (int s0 = 0; s0 < T_; s0 += 64){
    __syncthreads();                   // prev-iter LDS reads done
    #pragma unroll
    for (int r = 0; r < 4; r++){
      int rb = wid * 32 + r * 8;       // wave stages rows [wid*32, wid*32+32)
      glds16(kb + (size_t)(s0 + rb + grow) * DH_ + gcol, &Ks[rb * 64]);
      glds16(vb + (size_t)(rb + grow) * T_ + s0 + gcol, &Vt[rb * 64]);
    }
    __syncthreads();                   // drain DMA -> staged data visible

    // S^T = K.Q^T: A=K (shared across tg), B=Q^T. D: S^T[s=nt*16+quad*4+r][t=l15]
    f32x4 S[2][4];
    #pragma unroll
    for (int nt = 0; nt < 4; nt++){
      const int rowb = (nt * 16 + l15) * 64;
      bf16x8 ak0 = *(const bf16x8*)&Ks[rowb + ((quad ^ swf) * 8)];
      bf16x8 ak1 = *(const bf16x8*)&Ks[rowb + (((4 + quad) ^ swf) * 8)];
      #pragma unroll
      for (int tg = 0; tg < 2; tg++){
        f32x4 a; a[0]=0.f; a[1]=0.f; a[2]=0.f; a[3]=0.f;
        a = __builtin_amdgcn_mfma_f32_16x16x32_bf16(ak0, bq[tg][0], a, 0, 0, 0);
        a = __builtin_amdgcn_mfma_f32_16x16x32_bf16(ak1, bq[tg][1], a, 0, 0, 0);
        S[tg][nt] = a;
      }
    }

    // bias + exp2. Saturation: all |s-t| >= 128 in tile -> constant bias (exact bucket clamp).
    const int drel = s0 - t0w;         // wave-uniform
    if (drel >= 160 || drel <= -192){
      const float sv = (drel > 0) ? tabh[383] : tabh[127];   // rp=+128 / rp=-128 values
      #pragma unroll
      for (int tg = 0; tg < 2; tg++){
        const float cb = g[tg] * sv;
        #pragma unroll
        for (int nt = 0; nt < 4; nt++)
          #pragma unroll
          for (int r = 0; r < 4; r++)
            S[tg][nt][r] = __builtin_amdgcn_exp2f(S[tg][nt][r] + cb);
      }
    } else {
      #pragma unroll
      for (int tg = 0; tg < 2; tg++){
        const int ib = drel + 255 - tg * 16 - l15;   // window index: (s-t)+255
        #pragma unroll
        for (int nt = 0; nt < 4; nt++)
          #pragma unroll
          for (int r = 0; r < 4; r++)
            S[tg][nt][r] = __builtin_amdgcn_exp2f(S[tg][nt][r] + g[tg] * tabh[ib + nt * 16 + quad * 4 + r]);
      }
    }

    // P^T -> wave-local LDS (t-major); denominator off critical path
    #pragma unroll
    for (int tg = 0; tg < 2; tg++){
      __bf16* pw = &Pt[wid][tg][0];
      #pragma unroll
      for (int nt = 0; nt < 4; nt++){
        bf16x4 p;
        p[0] = f2bf_fast(S[tg][nt][0]); p[1] = f2bf_fast(S[tg][nt][1]);
        p[2] = f2bf_fast(S[tg][nt][2]); p[3] = f2bf_fast(S[tg][nt][3]);
        *(bf16x4*)&pw[l15 * LDP + nt * 16 + quad * 4] = p;
      }
      float rs = 0.f;
      #pragma unroll
      for (int nt = 0; nt < 4; nt++) rs += (S[tg][nt][0] + S[tg][nt][1]) + (S[tg][nt][2] + S[tg][nt][3]);
      rs += __shfl_xor(rs, 16, 64);
      rs += __shfl_xor(rs, 32, 64);
      l_run[tg] += rs;
    }

    // O^T += V^T.P^T: A=V^T (shared across tg, swizzled), B=P^T
    #pragma unroll
    for (int ks = 0; ks < 2; ks++){
      bf16x8 bp[2];
      #pragma unroll
      for (int tg = 0; tg < 2; tg++)
        bp[tg] = *(const bf16x8*)&Pt[wid][tg][l15 * LDP + ks * 32 + quad * 8];
      #pragma unroll
      for (int mt = 0; mt < 4; mt++){
        const int rowb = (mt * 16 + l15) * 64;
        bf16x8 av = *(const bf16x8*)&Vt[rowb + (((ks * 4 + quad) ^ swf) * 8)];
        #pragma unroll
        for (int tg = 0; tg < 2; tg++)
          O[tg][mt] = __builtin_amdgcn_mfma_f32_16x16x32_bf16(av, bp[tg], O[tg][mt], 0, 0, 0);
      }
    }
  }

  // epilogue: ctx[(t*B+b)*E + h*64+d], d = mt*16+quad*4+r
  #pragma unroll
  for (int tg = 0; tg < 2; tg++){
    const int t_lane = t0w + tg * 16 + l15;
    const float inv = 1.f / l_run[tg];
    #pragma unroll
    for (int mt = 0; mt < 4; mt++){
      bf16x4 o;
      o[0] = f2bf(O[tg][mt][0] * inv); o[1] = f2bf(O[tg][mt][1] * inv);
      o[2] = f2bf(O[tg][mt][2] * inv); o[3] = f2bf(O[tg][mt][3] * inv);
      *(bf16x4*)&ctx[(size_t)(t_lane * B_ + b) * E_ + h * DH_ + mt * 16 + quad * 4] = o;
    }
  }
}

extern "C" void kernel_launch(void* const* d_in, const int* in_sizes, int n_in,
                              void* d_out, int out_size, void* d_ws, size_t ws_size,
                              hipStream_t stream)
{
  (void)in_sizes; (void)n_in; (void)out_size; (void)ws_size;
  const float* query    = (const float*)d_in[0];
  const float* q_w      = (const float*)d_in[1];
  const float* q_b      = (const float*)d_in[2];
  const float* k_w      = (const float*)d_in[3];
  const float* k_b      = (const float*)d_in[4];
  const float* v_w      = (const float*)d_in[5];
  const float* v_b      = (const float*)d_in[6];
  const float* out_w    = (const float*)d_in[7];
  const float* out_b    = (const float*)d_in[8];
  const float* rel_bias = (const float*)d_in[9];
  const float* grep_w   = (const float*)d_in[10];
  const float* grep_b   = (const float*)d_in[11];
  const float* grep_a   = (const float*)d_in[12];

  char* ws = (char*)d_ws;
  size_t off = 0;
  __bf16* qbf = (__bf16*)(ws + off); off += (size_t)4096 * 1024 * 2;   // query bf16 (TB, E)
  __bf16* wq  = (__bf16*)(ws + off); off += (size_t)1024 * 1024 * 2;
  __bf16* wk  = (__bf16*)(ws + off); off += (size_t)1024 * 1024 * 2;
  __bf16* wv  = (__bf16*)(ws + off); off += (size_t)1024 * 1024 * 2;
  __bf16* wo  = (__bf16*)(ws + off); off += (size_t)1024 * 1024 * 2;
  __bf16* qh  = (__bf16*)(ws + off); off += (size_t)4096 * 1024 * 2;   // (B,H,T,DH)
  __bf16* kh  = (__bf16*)(ws + off); off += (size_t)4096 * 1024 * 2;   // (B,H,T,DH)
  __bf16* vhT = (__bf16*)(ws + off); off += (size_t)4096 * 1024 * 2;   // (B,H,DH,T)
  __bf16* ctx = (__bf16*)(ws + off); off += (size_t)4096 * 1024 * 2;   // (TB, E)
  float* gates = (float*)(ws + off); off += (size_t)65536 * 4;         // (B*H, T), * log2e
  float* tab   = (float*)(ws + off); off += (size_t)16 * 2047 * 4;     // (H, 2047) fp32

  prep_kernel<<<4480, 256, 0, stream>>>(q_w, k_w, v_w, out_w, wq, wk, wv, wo,
                                        query, grep_w, grep_b, grep_a, gates, qbf,
                                        rel_bias, tab);
  gemm_qkv<<<512, 256, 0, stream>>>(qbf, wq, wk, wv, q_b, k_b, v_b, qh, kh, vhT);
  attn_kernel<<<1024, 128, 0, stream>>>(qh, kh, vhT, gates, tab, ctx);
  gemm_out<<<512, 256, 0, stream>>>(ctx, wo, out_b, (float*)d_out);
}